// Round 4
// baseline (1249.826 us; speedup 1.0000x reference)
//
#include <hip/hip_runtime.h>
#include <hip/hip_bf16.h>
#include <stdint.h>

#define Bb 4
#define Ss 8192
#define Hh 2048
#define NHh 16
#define DHh 128
#define DFFf 8192
#define KS 1024
#define NTOK 4096

typedef unsigned short u16;
typedef __bf16 bf16x8 __attribute__((ext_vector_type(8)));
typedef float f32x4 __attribute__((ext_vector_type(4)));

union B8 { uint4 u; bf16x8 v; u16 s[8]; };

__device__ __forceinline__ float b2f(u16 x) { return __uint_as_float(((unsigned)x) << 16); }
__device__ __forceinline__ u16 f2b(float x) {
  __hip_bfloat16 h = __float2bfloat16(x);
  return *reinterpret_cast<u16*>(&h);
}

__device__ __forceinline__ void gll16(const void* g, void* l) {
  __builtin_amdgcn_global_load_lds((const __attribute__((address_space(1))) void*)g,
                                   (__attribute__((address_space(3))) void*)l, 16, 0, 0);
}

// swizzled 16B-unit index within a Rx32 bf16 region (row-pair XOR swizzle)
__device__ __forceinline__ int swz16(int r, int cg) {
  int u = ((r & 1) << 2) | cg;
  return ((r >> 1) << 3) | (u ^ ((r >> 1) & 7));
}

// ---------------- top-k index scan ----------------
__global__ void topk_prep(const void* maskp, const int* __restrict__ posids,
                          const float* __restrict__ scores,
                          int* __restrict__ idx, int* __restrict__ posg,
                          float* __restrict__ scalev) {
  int b = blockIdx.x;
  int tid = threadIdx.x, lane = tid & 63, wv = tid >> 6;
  __shared__ int wsum[4];
  __shared__ int base;
  __shared__ int mode;
  __shared__ int detCnt;
  if (tid == 0) { base = 0; detCnt = 0; }
  __syncthreads();
  {
    const unsigned char* mb = (const unsigned char*)maskp;
    int c = 0;
    for (int s = tid; s < 8192; s += 256) c += (mb[s] != 0);
    atomicAdd(&detCnt, c);
  }
  __syncthreads();
  if (tid == 0) mode = (detCnt == KS) ? 1 : 0;
  __syncthreads();
  const unsigned char* mb = (const unsigned char*)maskp;
  const int* mi = (const int*)maskp;
  for (int s0 = 0; s0 < Ss; s0 += 256) {
    int s = s0 + tid;
    int pred = mode ? (mb[(size_t)b * Ss + s] != 0) : (mi[(size_t)b * Ss + s] != 0);
    unsigned long long bal = __ballot(pred);
    int lp = __popcll(bal & ((1ull << lane) - 1ull));
    int wtot = __popcll(bal);
    if (lane == 0) wsum[wv] = wtot;
    __syncthreads();
    int woff = 0;
    for (int w = 0; w < wv; ++w) woff += wsum[w];
    int tot = wsum[0] + wsum[1] + wsum[2] + wsum[3];
    int p = base + woff + lp;
    if (pred && p < KS) {
      idx[b * KS + p] = s;
      posg[b * KS + p] = posids[(size_t)b * Ss + s];
    }
    __syncthreads();
    if (tid == 0) base += tot;
    __syncthreads();
  }
  if (b == 0 && tid < Bb) scalev[tid] = 0.5f * 1.0f + (scores[tid] - 0.5f) * 1.0f;
}

// ---------------- weight transpose fp32 -> bf16 ----------------
__global__ void transpose_w(const float* __restrict__ in, u16* __restrict__ out, int R, int C) {
  __shared__ float tile[32][33];
  int tx = threadIdx.x, ty = threadIdx.y;
  int c0 = blockIdx.x * 32, r0 = blockIdx.y * 32;
  for (int j = ty; j < 32; j += 8) tile[j][tx] = in[(size_t)(r0 + j) * C + c0 + tx];
  __syncthreads();
  for (int j = ty; j < 32; j += 8) out[(size_t)(c0 + j) * R + r0 + tx] = f2b(tile[tx][j]);
}

// ---------------- RMSNorm ----------------
template <int GATHER>
__global__ __launch_bounds__(256) void rmsnorm_k(const float* __restrict__ src0,
                                                 const int* __restrict__ idx,
                                                 const float* __restrict__ w,
                                                 u16* __restrict__ out) {
  int t = blockIdx.x;
  const float* src;
  if (GATHER) { int b = t >> 10; src = src0 + ((size_t)b * Ss + idx[t]) * Hh; }
  else src = src0 + (size_t)t * Hh;
  int tid = threadIdx.x, lane = tid & 63, wv = tid >> 6;
  float4 x0 = *(const float4*)(src + tid * 8);
  float4 x1 = *(const float4*)(src + tid * 8 + 4);
  float ss = x0.x * x0.x + x0.y * x0.y + x0.z * x0.z + x0.w * x0.w +
             x1.x * x1.x + x1.y * x1.y + x1.z * x1.z + x1.w * x1.w;
  for (int o = 32; o; o >>= 1) ss += __shfl_down(ss, o);
  __shared__ float wred[4];
  if (lane == 0) wred[wv] = ss;
  __syncthreads();
  float tot = wred[0] + wred[1] + wred[2] + wred[3];
  float r = rsqrtf(tot * (1.0f / Hh) + 1e-5f);
  const float* wp = w + tid * 8;
  u16* op = out + (size_t)t * Hh + tid * 8;
  float xs[8] = {x0.x, x0.y, x0.z, x0.w, x1.x, x1.y, x1.z, x1.w};
#pragma unroll
  for (int j = 0; j < 8; ++j) op[j] = f2b(xs[j] * r * wp[j]);
}

// ---------------- 256x256 8-phase bf16 GEMM (T1+T2+T3+T4+T5), B^T input ----------------
// Deep pipeline: stage lead 6 halves; guards vmcnt(8) at end of odd phases only
// (newest awaited load is 4 phases old). Grouped raster per XCD.
template <int EPI>
__global__ __launch_bounds__(512, 2) void gemm256(
    const u16* __restrict__ A, const u16* __restrict__ Bt,
    int N, int Kd, int lda, int gm, int gw,
    u16* __restrict__ Cb,
    const float* __restrict__ hid, const int* __restrict__ idx,
    const float* __restrict__ hs2, const float* __restrict__ scalev,
    float* __restrict__ Cf) {
  __shared__ u16 lds[65536];
  int bid = blockIdx.x;
  int xcd = bid & 7;
  int i = bid >> 3;
  int bm = i % gm;
  int bn = xcd * gw + i / gm;
  int m0 = bm * 256, n0 = bn * 256;
  int tid = threadIdx.x, lane = tid & 63, wv = tid >> 6;
  int wm = wv >> 2, wn = wv & 3;
  int NT = Kd >> 6;

  int P16 = wv * 64 + lane;
  int blk = P16 >> 3, up = P16 & 7;
  int uu = up ^ (blk & 7);
  int r0 = blk * 2 + (uu >> 2), cg0 = uu & 3;
  const u16* srcA = A + (size_t)(m0 + r0) * lda + cg0 * 8;
  const u16* srcB = Bt + (size_t)(n0 + r0) * Kd + cg0 * 8;
  size_t rsA = (size_t)128 * lda, rsB = (size_t)128 * Kd;

  int offA = swz16(wm * 128 + (lane & 15), lane >> 4) * 8;
  int offB = swz16(wn * 64 + (lane & 15), lane >> 4) * 8;

  auto stage = [&](int h) {
    int kt2 = h >> 2, j = h & 3;
    int isA = j & 1;
    int kk = j >> 1;
    int d = kt2 & 1;
    int reg = (isA ? 0 : 4) + d * 2 + kk;
    const u16* sp = (isA ? srcA : srcB) + kt2 * 64 + kk * 32;
    size_t rs = isA ? rsA : rsB;
    u16* dst = &lds[reg * 8192 + wv * 512];
    gll16(sp, dst);
    gll16(sp + rs, dst + 4096);
  };

  f32x4 acc[8][4] = {};
  B8 aR[4], bR[4];

  for (int h = 0; h < 6; ++h) stage(h);
  asm volatile("s_waitcnt vmcnt(8)" ::: "memory");
  asm volatile("s_barrier" ::: "memory");

  for (int kt = 0; kt < NT; ++kt) {
    int d = kt & 1;
    int g0 = kt * 4;
#pragma unroll
    for (int ph = 0; ph < 4; ++ph) {
      const int kk = ph >> 1, mh = ph & 1;
      if (mh == 0) {
#pragma unroll
        for (int nf = 0; nf < 4; ++nf)
          bR[nf].u = *(const uint4*)&lds[(4 + d * 2 + kk) * 8192 + offB + nf * 512];
      }
#pragma unroll
      for (int i2 = 0; i2 < 4; ++i2)
        aR[i2].u = *(const uint4*)&lds[(d * 2 + kk) * 8192 + offA + (i2 + 4 * mh) * 512];
      int h = g0 + ph + 6;
      if (h < 4 * NT) stage(h);
      asm volatile("s_barrier" ::: "memory");
      asm volatile("s_waitcnt lgkmcnt(0)" ::: "memory");
      __builtin_amdgcn_s_setprio(1);
#pragma unroll
      for (int nf = 0; nf < 4; ++nf)
#pragma unroll
        for (int i2 = 0; i2 < 4; ++i2)
          acc[mh * 4 + i2][nf] =
              __builtin_amdgcn_mfma_f32_16x16x32_bf16(aR[i2].v, bR[nf].v, acc[mh * 4 + i2][nf], 0, 0, 0);
      __builtin_amdgcn_s_setprio(0);
      if (ph == 1) {
        if (kt < NT - 1) asm volatile("s_waitcnt vmcnt(8)" ::: "memory");
        else asm volatile("s_waitcnt vmcnt(0)" ::: "memory");
      } else if (ph == 3) {
        if (kt < NT - 2) asm volatile("s_waitcnt vmcnt(8)" ::: "memory");
        else if (kt == NT - 2) asm volatile("s_waitcnt vmcnt(4)" ::: "memory");
      }
      asm volatile("s_barrier" ::: "memory");
    }
  }

#pragma unroll
  for (int mf = 0; mf < 8; ++mf) {
#pragma unroll
    for (int rr = 0; rr < 4; ++rr) {
      int row = m0 + wm * 128 + mf * 16 + (lane >> 4) * 4 + rr;
#pragma unroll
      for (int nf = 0; nf < 4; ++nf) {
        int col = n0 + wn * 64 + nf * 16 + (lane & 15);
        float v = acc[mf][nf][rr];
        if (EPI == 0) {
          Cb[(size_t)row * N + col] = f2b(v);
        } else if (EPI == 1) {
          int b = row >> 10;
          Cf[(size_t)row * Hh + col] = hid[((size_t)b * Ss + idx[row]) * Hh + col] + v;
        } else {
          int b = row >> 10;
          Cf[((size_t)b * Ss + idx[row]) * Hh + col] = hs2[(size_t)row * Hh + col] + v * scalev[b];
        }
      }
    }
  }
}

// ---------------- 128x256 bf16 GEMM, 6-slot deep pipeline, same discipline ----------------
// 6 half-K slots (A 8KB + B 16KB each = 144KB LDS). Stage lead 5 phases; vmcnt(12)
// per phase (4 stages x 3 loads outstanding); tail 12/9/6/3/0.
template <int EPI>
__global__ __launch_bounds__(512, 1) void gemm128(
    const u16* __restrict__ A, const u16* __restrict__ Bt,
    int N, int Kd, int lda, int gm, int gw,
    u16* __restrict__ Cb,
    const float* __restrict__ hid, const int* __restrict__ idx,
    const float* __restrict__ hs2, const float* __restrict__ scalev,
    float* __restrict__ Cf) {
  __shared__ u16 lds[73728];
  int bid = blockIdx.x;
  int xcd = bid & 7;
  int i = bid >> 3;
  int bm = i % gm;
  int bn = xcd * gw + i / gm;
  int m0 = bm * 128, n0 = bn * 256;
  int tid = threadIdx.x, lane = tid & 63, wv = tid >> 6;
  int wm = wv >> 2, wn = wv & 3;
  int NT = Kd >> 6;
  int P = NT * 2;

  int P16 = wv * 64 + lane;
  int blk = P16 >> 3, up = P16 & 7;
  int uu = up ^ (blk & 7);
  int r0 = blk * 2 + (uu >> 2), cg0 = uu & 3;
  const u16* srcA = A + (size_t)(m0 + r0) * lda + cg0 * 8;
  const u16* srcB = Bt + (size_t)(n0 + r0) * Kd + cg0 * 8;
  size_t rsB = (size_t)128 * Kd;

  int offAr[4], offBr[4];
#pragma unroll
  for (int f = 0; f < 4; ++f) {
    offAr[f] = swz16(wm * 64 + f * 16 + (lane & 15), lane >> 4) * 8;
    offBr[f] = swz16(wn * 64 + f * 16 + (lane & 15), lane >> 4) * 8;
  }

  auto stage = [&](int q) {
    int kt = q >> 1, kk = q & 1;
    int slot = q % 6;
    const u16* spB = srcB + kt * 64 + kk * 32;
    u16* dstB = &lds[24576 + slot * 8192 + wv * 512];
    gll16(spB, dstB);
    gll16(spB + rsB, dstB + 4096);
    gll16(srcA + kt * 64 + kk * 32, &lds[slot * 4096 + wv * 512]);
  };

  f32x4 acc[4][4] = {};
  B8 aR[4], bR[4];

  for (int q = 0; q < 5; ++q) stage(q);
  asm volatile("s_waitcnt vmcnt(12)" ::: "memory");
  asm volatile("s_barrier" ::: "memory");

  for (int p = 0; p < P; ++p) {
    int slot = p % 6;
    int baseA = slot * 4096;
    int baseB = 24576 + slot * 8192;
#pragma unroll
    for (int f = 0; f < 4; ++f) aR[f].u = *(const uint4*)&lds[baseA + offAr[f]];
#pragma unroll
    for (int f = 0; f < 4; ++f) bR[f].u = *(const uint4*)&lds[baseB + offBr[f]];
    int q = p + 5;
    if (q < P) stage(q);
    asm volatile("s_barrier" ::: "memory");
    asm volatile("s_waitcnt lgkmcnt(0)" ::: "memory");
    __builtin_amdgcn_s_setprio(1);
#pragma unroll
    for (int nf = 0; nf < 4; ++nf)
#pragma unroll
      for (int mf = 0; mf < 4; ++mf)
        acc[mf][nf] = __builtin_amdgcn_mfma_f32_16x16x32_bf16(aR[mf].v, bR[nf].v, acc[mf][nf], 0, 0, 0);
    __builtin_amdgcn_s_setprio(0);
    {
      int rem = P - 2 - p;  // stages still needed after this phase
      if (rem >= 4) asm volatile("s_waitcnt vmcnt(12)" ::: "memory");
      else if (rem == 3) asm volatile("s_waitcnt vmcnt(9)" ::: "memory");
      else if (rem == 2) asm volatile("s_waitcnt vmcnt(6)" ::: "memory");
      else if (rem == 1) asm volatile("s_waitcnt vmcnt(3)" ::: "memory");
      else if (rem == 0) asm volatile("s_waitcnt vmcnt(0)" ::: "memory");
    }
    asm volatile("s_barrier" ::: "memory");
  }

#pragma unroll
  for (int mf = 0; mf < 4; ++mf) {
#pragma unroll
    for (int rr = 0; rr < 4; ++rr) {
      int row = m0 + wm * 64 + mf * 16 + (lane >> 4) * 4 + rr;
#pragma unroll
      for (int nf = 0; nf < 4; ++nf) {
        int col = n0 + wn * 64 + nf * 16 + (lane & 15);
        float v = acc[mf][nf][rr];
        if (EPI == 0) {
          Cb[(size_t)row * N + col] = f2b(v);
        } else if (EPI == 1) {
          int b = row >> 10;
          Cf[(size_t)row * Hh + col] = hid[((size_t)b * Ss + idx[row]) * Hh + col] + v;
        } else {
          int b = row >> 10;
          Cf[((size_t)b * Ss + idx[row]) * Hh + col] = hs2[(size_t)row * Hh + col] + v * scalev[b];
        }
      }
    }
  }
}

// ---------------- RoPE on fused QKV buffer (stride 6144) ----------------
__global__ __launch_bounds__(256) void rope_qk(u16* __restrict__ qkv,
                                               const int* __restrict__ posg) {
  int gid = blockIdx.x * 256 + threadIdx.x;
  int i = gid & 63;
  int h = (gid >> 6) & 15;
  int t = gid >> 10;
  float p = (float)posg[t];
  float inv = exp2f(-(float)i * (13.287712379549449f / 64.0f));
  float ang = p * inv;
  float sv, cv;
  sincosf(ang, &sv, &cv);
  size_t base = (size_t)t * 6144 + h * DHh + i;
  u16* Q = qkv;
  u16* Kq = qkv + 2048;
  float q1 = b2f(Q[base]), q2 = b2f(Q[base + 64]);
  Q[base] = f2b(q1 * cv - q2 * sv);
  Q[base + 64] = f2b(q2 * cv + q1 * sv);
  float k1 = b2f(Kq[base]), k2 = b2f(Kq[base + 64]);
  Kq[base] = f2b(k1 * cv - k2 * sv);
  Kq[base + 64] = f2b(k2 * cv + k1 * sv);
}

// ---------------- flash attention over fused QKV (stride 6144) ----------------
__global__ __launch_bounds__(256) void attn_k(const u16* __restrict__ QKV, u16* __restrict__ O) {
  int qb = blockIdx.x;
  int head = blockIdx.y;
  int b = head >> 4, h = head & 15;
  int tid = threadIdx.x, lane = tid & 63, wv = tid >> 6;
  __shared__ __align__(16) u16 Ksm[32][136];
  __shared__ __align__(16) u16 Vs[128][40];
  __shared__ __align__(16) u16 Ps[4][16][40];
  int q0 = qb * 64 + wv * 16;
  int tokQ = b * KS + q0;
  B8 qf[4];
  const u16* qp = QKV + (size_t)(tokQ + (lane & 15)) * 6144 + h * DHh;
#pragma unroll
  for (int c = 0; c < 4; ++c) qf[c].u = *(const uint4*)(qp + c * 32 + (lane >> 4) * 8);
  float m_run = -1e30f, l_run = 0.0f;
  f32x4 oacc[8] = {};
  int kmax = qb * 64 + 64;
  for (int ks = 0; ks < kmax; ks += 32) {
    __syncthreads();
    for (int s = tid; s < 512; s += 256) {
      int key = s >> 4, d0 = (s & 15) * 8;
      size_t gb = (size_t)(b * KS + ks + key) * 6144 + 2048 + h * DHh + d0;
      uint4 kv = *(const uint4*)(QKV + gb);
      *(uint4*)&Ksm[key][d0] = kv;
      uint4 vv = *(const uint4*)(QKV + gb + 2048);
      u16* vp = (u16*)&vv;
      int kb = key >> 3, ko = key & 7;
#pragma unroll
      for (int j = 0; j < 8; ++j) {
        int d = d0 + j;
        Vs[d][((kb ^ ((d >> 3) & 3)) << 3) | ko] = vp[j];
      }
    }
    __syncthreads();
    f32x4 st[2] = {};
#pragma unroll
    for (int c = 0; c < 4; ++c) {
      B8 k0f, k1f;
      k0f.u = *(const uint4*)&Ksm[lane & 15][c * 32 + (lane >> 4) * 8];
      k1f.u = *(const uint4*)&Ksm[16 + (lane & 15)][c * 32 + (lane >> 4) * 8];
      st[0] = __builtin_amdgcn_mfma_f32_16x16x32_bf16(k0f.v, qf[c].v, st[0], 0, 0, 0);
      st[1] = __builtin_amdgcn_mfma_f32_16x16x32_bf16(k1f.v, qf[c].v, st[1], 0, 0, 0);
    }
    int qi = q0 + (lane & 15);
    float pmax = -INFINITY;
#pragma unroll
    for (int kt = 0; kt < 2; ++kt)
#pragma unroll
      for (int r = 0; r < 4; ++r) {
        int ki = ks + kt * 16 + (lane >> 4) * 4 + r;
        float v = st[kt][r] * 0.088388347648318447f;
        v = (ki <= qi) ? v : -INFINITY;
        st[kt][r] = v;
        pmax = fmaxf(pmax, v);
      }
    pmax = fmaxf(pmax, __shfl_xor(pmax, 16));
    pmax = fmaxf(pmax, __shfl_xor(pmax, 32));
    float m_new = fmaxf(m_run, pmax);
    float alpha = __expf(m_run - m_new);
    float psum = 0.0f;
#pragma unroll
    for (int kt = 0; kt < 2; ++kt)
#pragma unroll
      for (int r = 0; r < 4; ++r) {
        float pv = __expf(st[kt][r] - m_new);
        st[kt][r] = pv;
        psum += pv;
      }
    psum += __shfl_xor(psum, 16);
    psum += __shfl_xor(psum, 32);
    l_run = l_run * alpha + psum;
    m_run = m_new;
#pragma unroll
    for (int kt = 0; kt < 2; ++kt) {
      ushort4 pk;
      pk.x = f2b(st[kt][0]); pk.y = f2b(st[kt][1]);
      pk.z = f2b(st[kt][2]); pk.w = f2b(st[kt][3]);
      *(ushort4*)&Ps[wv][lane & 15][kt * 16 + (lane >> 4) * 4] = pk;
    }
    B8 pf;
    pf.u = *(const uint4*)&Ps[wv][lane & 15][(lane >> 4) * 8];
    float al0 = __shfl(alpha, (lane >> 4) * 4 + 0);
    float al1 = __shfl(alpha, (lane >> 4) * 4 + 1);
    float al2 = __shfl(alpha, (lane >> 4) * 4 + 2);
    float al3 = __shfl(alpha, (lane >> 4) * 4 + 3);
#pragma unroll
    for (int dt = 0; dt < 8; ++dt) {
      oacc[dt][0] *= al0; oacc[dt][1] *= al1;
      oacc[dt][2] *= al2; oacc[dt][3] *= al3;
    }
#pragma unroll
    for (int dt = 0; dt < 8; ++dt) {
      int d = dt * 16 + (lane & 15);
      B8 vf;
      vf.u = *(const uint4*)&Vs[d][(((lane >> 4) ^ ((d >> 3) & 3)) << 3)];
      oacc[dt] = __builtin_amdgcn_mfma_f32_16x16x32_bf16(pf.v, vf.v, oacc[dt], 0, 0, 0);
    }
  }
  float linv = 1.0f / l_run;
  float li[4];
#pragma unroll
  for (int r = 0; r < 4; ++r) li[r] = __shfl(linv, (lane >> 4) * 4 + r);
#pragma unroll
  for (int r = 0; r < 4; ++r) {
    int tok = tokQ + (lane >> 4) * 4 + r;
    u16* op = O + (size_t)tok * Hh + h * DHh;
#pragma unroll
    for (int dt = 0; dt < 8; ++dt) op[dt * 16 + (lane & 15)] = f2b(oacc[dt][r] * li[r]);
  }
}

// ---------------- silu(g)*u on fused gate|up buffer (stride 16384) ----------------
__global__ __launch_bounds__(256) void silu_gu(u16* __restrict__ gu) {
  size_t gid = (size_t)blockIdx.x * 256 + threadIdx.x;
  size_t t = gid >> 10;
  int c = (int)(gid & 1023) * 8;
  u16* gp = gu + t * 16384 + c;
  const u16* upp = gp + 8192;
  B8 gv, uv;
  gv.u = *(const uint4*)gp;
  uv.u = *(const uint4*)upp;
#pragma unroll
  for (int j = 0; j < 8; ++j) {
    float x = b2f(gv.s[j]), y = b2f(uv.s[j]);
    gv.s[j] = f2b(x / (1.0f + __expf(-x)) * y);
  }
  *(uint4*)gp = gv.u;
}

extern "C" void kernel_launch(void* const* d_in, const int* in_sizes, int n_in,
                              void* d_out, int out_size, void* d_ws, size_t ws_size,
                              hipStream_t stream) {
  (void)in_sizes; (void)n_in; (void)out_size; (void)ws_size;
  const float* hid = (const float*)d_in[0];
  const int* posids = (const int*)d_in[1];
  const void* mask = d_in[2];
  const float* scores = (const float*)d_in[3];
  const float* Wq = (const float*)d_in[5];
  const float* Wk = (const float*)d_in[6];
  const float* Wv = (const float*)d_in[7];
  const float* Wo = (const float*)d_in[8];
  const float* Wg = (const float*)d_in[9];
  const float* Wu = (const float*)d_in[10];
  const float* Wd = (const float*)d_in[11];
  const float* ln1 = (const float*)d_in[12];
  const float* ln2 = (const float*)d_in[13];
  float* out = (float*)d_out;
  char* ws = (char*)d_ws;

  u16* WqkvT = (u16*)(ws + 0);            // [6144][2048] bf16
  u16* WoT   = (u16*)(ws + 25165824);     // [2048][2048]
  u16* WguT  = (u16*)(ws + 33554432);     // [16384][2048]
  u16* WdT   = (u16*)(ws + 100663296);    // [2048][8192]
  int* idx   = (int*)(ws + 134217728);
  int* posg  = (int*)(ws + 134217728 + 16384);
  float* scalev = (float*)(ws + 134217728 + 32768);
  char* R = ws + 134283264;               // 128MiB pool
  u16* hsn    = (u16*)(R);                // [4096][2048]
  u16* qkv    = (u16*)(R + 16777216);     // [4096][6144]
  u16* attn_o = (u16*)(R + 67108864);     // [4096][2048]
  u16* gu     = (u16*)(R);                // [4096][16384] overlays (dead by then)
  float* hs2  = (float*)(ws + 268500992); // [4096][2048] f32
  u16* mnorm  = (u16*)(ws + 302055424);   // [4096][2048]

  hipMemcpyAsync(out, hid, (size_t)Bb * Ss * Hh * 4, hipMemcpyDeviceToDevice, stream);

  topk_prep<<<Bb, 256, 0, stream>>>(mask, posids, scores, idx, posg, scalev);

  transpose_w<<<dim3(64, 64), dim3(32, 8), 0, stream>>>(Wq, WqkvT, 2048, 2048);
  transpose_w<<<dim3(64, 64), dim3(32, 8), 0, stream>>>(Wk, WqkvT + 2048 * 2048, 2048, 2048);
  transpose_w<<<dim3(64, 64), dim3(32, 8), 0, stream>>>(Wv, WqkvT + 4096 * 2048, 2048, 2048);
  transpose_w<<<dim3(64, 64), dim3(32, 8), 0, stream>>>(Wo, WoT, 2048, 2048);
  transpose_w<<<dim3(256, 64), dim3(32, 8), 0, stream>>>(Wg, WguT, 2048, 8192);
  transpose_w<<<dim3(256, 64), dim3(32, 8), 0, stream>>>(Wu, WguT + 8192 * 2048, 2048, 8192);
  transpose_w<<<dim3(64, 256), dim3(32, 8), 0, stream>>>(Wd, WdT, 8192, 2048);

  rmsnorm_k<1><<<NTOK, 256, 0, stream>>>(hid, idx, ln1, hsn);

  // QKV fused: [4096,2048] x [2048,6144] -> qkv   (BM=128: 32x24=768 blocks, gw=3)
  gemm128<0><<<768, 512, 0, stream>>>(hsn, WqkvT, 6144, 2048, 2048, 32, 3, qkv,
                                      nullptr, nullptr, nullptr, nullptr, nullptr);

  rope_qk<<<16384, 256, 0, stream>>>(qkv, posg);

  attn_k<<<dim3(16, 64), 256, 0, stream>>>(qkv, attn_o);

  // Wo: attn_o x WoT -> hs2 (BM=128: 32x8=256 blocks, gw=1)
  gemm128<1><<<256, 512, 0, stream>>>(attn_o, WoT, 2048, 2048, 2048, 32, 1, nullptr,
                                      hid, idx, nullptr, nullptr, hs2);

  rmsnorm_k<0><<<NTOK, 256, 0, stream>>>(hs2, nullptr, ln2, mnorm);

  // gate|up fused: mnorm x WguT -> gu (BM=256: 16x64=1024 blocks, gw=8)
  gemm256<0><<<1024, 512, 0, stream>>>(mnorm, WguT, 16384, 2048, 2048, 16, 8, gu,
                                       nullptr, nullptr, nullptr, nullptr, nullptr);

  silu_gu<<<16384, 256, 0, stream>>>(gu);

  // down: gu(g half, lda=16384) x WdT -> out (BM=128: 32x8=256 blocks, gw=1)
  gemm128<2><<<256, 512, 0, stream>>>(gu, WdT, 2048, 8192, 16384, 32, 1, nullptr,
                                      nullptr, idx, hs2, scalev, out);
}

// Round 6
// 1218.087 us; speedup vs baseline: 1.0261x; 1.0261x over previous
//
#include <hip/hip_runtime.h>
#include <hip/hip_bf16.h>
#include <stdint.h>

#define Bb 4
#define Ss 8192
#define Hh 2048
#define NHh 16
#define DHh 128
#define DFFf 8192
#define KS 1024
#define NTOK 4096

typedef unsigned short u16;
typedef __bf16 bf16x8 __attribute__((ext_vector_type(8)));
typedef float f32x4 __attribute__((ext_vector_type(4)));

union B8 { uint4 u; bf16x8 v; u16 s[8]; };

__device__ __forceinline__ float b2f(u16 x) { return __uint_as_float(((unsigned)x) << 16); }
__device__ __forceinline__ u16 f2b(float x) {
  __hip_bfloat16 h = __float2bfloat16(x);
  return *reinterpret_cast<u16*>(&h);
}

__device__ __forceinline__ void gll16(const void* g, void* l) {
  __builtin_amdgcn_global_load_lds((const __attribute__((address_space(1))) void*)g,
                                   (__attribute__((address_space(3))) void*)l, 16, 0, 0);
}

// swizzled 16B-unit index within a Rx32 bf16 region (row-pair XOR swizzle)
__device__ __forceinline__ int swz16(int r, int cg) {
  int u = ((r & 1) << 2) | cg;
  return ((r >> 1) << 3) | (u ^ ((r >> 1) & 7));
}

// ---------------- top-k index scan ----------------
__global__ void topk_prep(const void* maskp, const int* __restrict__ posids,
                          const float* __restrict__ scores,
                          int* __restrict__ idx, int* __restrict__ posg,
                          float* __restrict__ scalev) {
  int b = blockIdx.x;
  int tid = threadIdx.x, lane = tid & 63, wv = tid >> 6;
  __shared__ int wsum[4];
  __shared__ int base;
  __shared__ int mode;
  __shared__ int detCnt;
  if (tid == 0) { base = 0; detCnt = 0; }
  __syncthreads();
  {
    const unsigned char* mb = (const unsigned char*)maskp;
    int c = 0;
    for (int s = tid; s < 8192; s += 256) c += (mb[s] != 0);
    atomicAdd(&detCnt, c);
  }
  __syncthreads();
  if (tid == 0) mode = (detCnt == KS) ? 1 : 0;
  __syncthreads();
  const unsigned char* mb = (const unsigned char*)maskp;
  const int* mi = (const int*)maskp;
  for (int s0 = 0; s0 < Ss; s0 += 256) {
    int s = s0 + tid;
    int pred = mode ? (mb[(size_t)b * Ss + s] != 0) : (mi[(size_t)b * Ss + s] != 0);
    unsigned long long bal = __ballot(pred);
    int lp = __popcll(bal & ((1ull << lane) - 1ull));
    int wtot = __popcll(bal);
    if (lane == 0) wsum[wv] = wtot;
    __syncthreads();
    int woff = 0;
    for (int w = 0; w < wv; ++w) woff += wsum[w];
    int tot = wsum[0] + wsum[1] + wsum[2] + wsum[3];
    int p = base + woff + lp;
    if (pred && p < KS) {
      idx[b * KS + p] = s;
      posg[b * KS + p] = posids[(size_t)b * Ss + s];
    }
    __syncthreads();
    if (tid == 0) base += tot;
    __syncthreads();
  }
  if (b == 0 && tid < Bb) scalev[tid] = 0.5f * 1.0f + (scores[tid] - 0.5f) * 1.0f;
}

// ---------------- weight transpose fp32 -> bf16 ----------------
__global__ void transpose_w(const float* __restrict__ in, u16* __restrict__ out, int R, int C) {
  __shared__ float tile[32][33];
  int tx = threadIdx.x, ty = threadIdx.y;
  int c0 = blockIdx.x * 32, r0 = blockIdx.y * 32;
  for (int j = ty; j < 32; j += 8) tile[j][tx] = in[(size_t)(r0 + j) * C + c0 + tx];
  __syncthreads();
  for (int j = ty; j < 32; j += 8) out[(size_t)(c0 + j) * R + r0 + tx] = f2b(tile[tx][j]);
}

// ---------------- RMSNorm ----------------
template <int GATHER>
__global__ __launch_bounds__(256) void rmsnorm_k(const float* __restrict__ src0,
                                                 const int* __restrict__ idx,
                                                 const float* __restrict__ w,
                                                 u16* __restrict__ out) {
  int t = blockIdx.x;
  const float* src;
  if (GATHER) { int b = t >> 10; src = src0 + ((size_t)b * Ss + idx[t]) * Hh; }
  else src = src0 + (size_t)t * Hh;
  int tid = threadIdx.x, lane = tid & 63, wv = tid >> 6;
  float4 x0 = *(const float4*)(src + tid * 8);
  float4 x1 = *(const float4*)(src + tid * 8 + 4);
  float ss = x0.x * x0.x + x0.y * x0.y + x0.z * x0.z + x0.w * x0.w +
             x1.x * x1.x + x1.y * x1.y + x1.z * x1.z + x1.w * x1.w;
  for (int o = 32; o; o >>= 1) ss += __shfl_down(ss, o);
  __shared__ float wred[4];
  if (lane == 0) wred[wv] = ss;
  __syncthreads();
  float tot = wred[0] + wred[1] + wred[2] + wred[3];
  float r = rsqrtf(tot * (1.0f / Hh) + 1e-5f);
  const float* wp = w + tid * 8;
  u16* op = out + (size_t)t * Hh + tid * 8;
  float xs[8] = {x0.x, x0.y, x0.z, x0.w, x1.x, x1.y, x1.z, x1.w};
#pragma unroll
  for (int j = 0; j < 8; ++j) op[j] = f2b(xs[j] * r * wp[j]);
}

// ---------------- 256x256 8-phase bf16 GEMM, pair-unrolled, const offsets ----------------
// LDS elem layout: A regions (d*2+kk)*8192 at 0..32768; B at 32768+(d*2+kk)*8192.
// Stage order (lead 7 halves): per K-tile {B.kk0,A.kk0,B.kk1,A.kk1}; vmcnt(6) at ph3.
template <int EPI>
__global__ __launch_bounds__(512, 2) void gemm256(
    const u16* __restrict__ A, const u16* __restrict__ Bt,
    int N, int Kd, int lda, int gm, int gw,
    u16* __restrict__ Cb,
    const float* __restrict__ hid, const int* __restrict__ idx,
    const float* __restrict__ hs2, const float* __restrict__ scalev,
    float* __restrict__ Cf) {
  __shared__ u16 lds[65536];
  int bid = blockIdx.x;
  int xcd = bid & 7;
  int i2 = bid >> 3;
  int bm = i2 / gw;             // bn-fast within XCD strip
  int bn = xcd * gw + i2 % gw;
  int m0 = bm * 256, n0 = bn * 256;
  int tid = threadIdx.x, lane = tid & 63, wv = tid >> 6;
  int wm = wv >> 2, wn = wv & 3;
  int NT = Kd >> 6;

  int P16 = wv * 64 + lane;
  int blk = P16 >> 3, up = P16 & 7;
  int uu = up ^ (blk & 7);
  int r0 = blk * 2 + (uu >> 2), cg0 = uu & 3;
  const u16* srcA = A + (size_t)(m0 + r0) * lda + cg0 * 8;
  const u16* srcB = Bt + (size_t)(n0 + r0) * Kd + cg0 * 8;
  size_t rsA = (size_t)128 * lda, rsB = (size_t)128 * Kd;

  int offA = swz16(wm * 128 + (lane & 15), lane >> 4) * 8;
  int offB = 32768 + swz16(wn * 64 + (lane & 15), lane >> 4) * 8;
  u16* ldsw = &lds[wv * 512];

  f32x4 acc[8][4] = {};
  B8 aR[4], bR[4];

  // prologue: 7 halves (t0 full, t1 minus A.kk1)
  gll16(srcB,      ldsw + 32768); gll16(srcB + rsB,      ldsw + 36864);
  gll16(srcA,      ldsw +     0); gll16(srcA + rsA,      ldsw +  4096);
  gll16(srcB + 32, ldsw + 40960); gll16(srcB + 32 + rsB, ldsw + 45056);
  gll16(srcA + 32, ldsw +  8192); gll16(srcA + 32 + rsA, ldsw + 12288);
  gll16(srcB + 64, ldsw + 49152); gll16(srcB + 64 + rsB, ldsw + 53248);
  gll16(srcA + 64, ldsw + 16384); gll16(srcA + 64 + rsA, ldsw + 20480);
  gll16(srcB + 96, ldsw + 57344); gll16(srcB + 96 + rsB, ldsw + 61440);
  asm volatile("s_waitcnt vmcnt(6)" ::: "memory");
  asm volatile("s_barrier" ::: "memory");

  const u16* stA = srcA + 64;
  const u16* stB = srcB + 64;

  auto phase = [&](int abase, int bbase, int mh) {
    if (mh == 0) {
#pragma unroll
      for (int nf = 0; nf < 4; ++nf) bR[nf].u = *(const uint4*)&lds[offB + bbase + nf * 512];
    }
#pragma unroll
    for (int i3 = 0; i3 < 4; ++i3)
      aR[i3].u = *(const uint4*)&lds[offA + abase + (i3 + 4 * mh) * 512];
  };
  auto mfma16 = [&](int mh) {
    asm volatile("s_barrier" ::: "memory");
    asm volatile("s_waitcnt lgkmcnt(0)" ::: "memory");
    __builtin_amdgcn_s_setprio(1);
#pragma unroll
    for (int nf = 0; nf < 4; ++nf)
#pragma unroll
      for (int i3 = 0; i3 < 4; ++i3)
        acc[mh * 4 + i3][nf] =
            __builtin_amdgcn_mfma_f32_16x16x32_bf16(aR[i3].v, bR[nf].v, acc[mh * 4 + i3][nf], 0, 0, 0);
    __builtin_amdgcn_s_setprio(0);
  };

  for (int ktp = 0; ktp < NT; ktp += 2) {
    bool sAll = (ktp < NT - 2);
    // ===== even body (d=0): A kk0@0 kk1@8192, B kk0@+0 kk1@+8192 =====
    phase(0, 0, 0);
    { gll16(stA + 32, ldsw + 24576); gll16(stA + 32 + rsA, ldsw + 28672); }  // A.kk1 t+1 (d1)
    mfma16(0);
    asm volatile("s_barrier" ::: "memory");
    phase(0, 0, 1);
    if (sAll) { gll16(stB + 64, ldsw + 32768); gll16(stB + 64 + rsB, ldsw + 36864); }  // B.kk0 t+2
    mfma16(1);
    asm volatile("s_barrier" ::: "memory");
    phase(8192, 8192, 0);
    if (sAll) { gll16(stA + 64, ldsw + 0); gll16(stA + 64 + rsA, ldsw + 4096); }       // A.kk0 t+2
    mfma16(0);
    asm volatile("s_barrier" ::: "memory");
    phase(8192, 8192, 1);
    if (sAll) { gll16(stB + 96, ldsw + 40960); gll16(stB + 96 + rsB, ldsw + 45056); }  // B.kk1 t+2
    mfma16(1);
    if (sAll) asm volatile("s_waitcnt vmcnt(6)" ::: "memory");
    else asm volatile("s_waitcnt vmcnt(0)" ::: "memory");
    asm volatile("s_barrier" ::: "memory");
    // ===== odd body (d=1): A kk0@16384 kk1@24576, B +16384/+24576 =====
    phase(16384, 16384, 0);
    if (sAll) { gll16(stA + 96, ldsw + 8192); gll16(stA + 96 + rsA, ldsw + 12288); }   // A.kk1 t+2 (d0)
    mfma16(0);
    asm volatile("s_barrier" ::: "memory");
    phase(16384, 16384, 1);
    if (sAll) { gll16(stB + 128, ldsw + 49152); gll16(stB + 128 + rsB, ldsw + 53248); }  // B.kk0 t+3
    mfma16(1);
    asm volatile("s_barrier" ::: "memory");
    phase(24576, 24576, 0);
    if (sAll) { gll16(stA + 128, ldsw + 16384); gll16(stA + 128 + rsA, ldsw + 20480); }  // A.kk0 t+3
    mfma16(0);
    asm volatile("s_barrier" ::: "memory");
    phase(24576, 24576, 1);
    if (sAll) { gll16(stB + 160, ldsw + 57344); gll16(stB + 160 + rsB, ldsw + 61440); }  // B.kk1 t+3
    mfma16(1);
    if (sAll) asm volatile("s_waitcnt vmcnt(6)" ::: "memory");
    asm volatile("s_barrier" ::: "memory");
    stA += 128; stB += 128;
  }

#pragma unroll
  for (int mf = 0; mf < 8; ++mf) {
#pragma unroll
    for (int rr = 0; rr < 4; ++rr) {
      int row = m0 + wm * 128 + mf * 16 + (lane >> 4) * 4 + rr;
#pragma unroll
      for (int nf = 0; nf < 4; ++nf) {
        int col = n0 + wn * 64 + nf * 16 + (lane & 15);
        float v = acc[mf][nf][rr];
        if (EPI == 0) {
          Cb[(size_t)row * N + col] = f2b(v);
        } else if (EPI == 1) {
          int b = row >> 10;
          Cf[(size_t)row * Hh + col] = hid[((size_t)b * Ss + idx[row]) * Hh + col] + v;
        } else {
          int b = row >> 10;
          Cf[((size_t)b * Ss + idx[row]) * Hh + col] = hs2[(size_t)row * Hh + col] + v * scalev[b];
        }
      }
    }
  }
}

// ---------------- 128x256 bf16 GEMM, 4-slot pipeline, pair-unrolled ----------------
// LDS elem layout: B slots s*8192 at 0..32768; A slots 32768+s*4096. 96KB.
// Stage = 3 gll16 (B 2 halves + A). Lead 3 phases; vmcnt(6)/3/0 tail.
template <int EPI>
__global__ __launch_bounds__(512, 2) void gemm128(
    const u16* __restrict__ A, const u16* __restrict__ Bt,
    int N, int Kd, int lda, int gm, int gw,
    u16* __restrict__ Cb,
    const float* __restrict__ hid, const int* __restrict__ idx,
    const float* __restrict__ hs2, const float* __restrict__ scalev,
    float* __restrict__ Cf) {
  __shared__ u16 lds[49152];
  int bid = blockIdx.x;
  int xcd = bid & 7;
  int i2 = bid >> 3;
  int bm = i2 / gw;
  int bn = xcd * gw + i2 % gw;
  int m0 = bm * 128, n0 = bn * 256;
  int tid = threadIdx.x, lane = tid & 63, wv = tid >> 6;
  int wm = wv >> 2, wn = wv & 3;
  int NT = Kd >> 6;

  int P16 = wv * 64 + lane;
  int blk = P16 >> 3, up = P16 & 7;
  int uu = up ^ (blk & 7);
  int r0 = blk * 2 + (uu >> 2), cg0 = uu & 3;
  const u16* srcA = A + (size_t)(m0 + r0) * lda + cg0 * 8;
  const u16* srcB = Bt + (size_t)(n0 + r0) * Kd + cg0 * 8;
  size_t rsB = (size_t)128 * Kd;

  int offB = swz16(wn * 64 + (lane & 15), lane >> 4) * 8;
  int offA = 32768 + swz16(wm * 64 + (lane & 15), lane >> 4) * 8;
  u16* ldsw = &lds[wv * 512];

  f32x4 acc[4][4] = {};
  B8 aR[4], bR[4];

  // prologue: stages q=0..2 -> slots 0..2
  gll16(srcB,      ldsw +     0); gll16(srcB + rsB,      ldsw +  4096); gll16(srcA,      ldsw + 32768);
  gll16(srcB + 32, ldsw +  8192); gll16(srcB + 32 + rsB, ldsw + 12288); gll16(srcA + 32, ldsw + 36864);
  gll16(srcB + 64, ldsw + 16384); gll16(srcB + 64 + rsB, ldsw + 20480); gll16(srcA + 64, ldsw + 40960);
  asm volatile("s_waitcnt vmcnt(6)" ::: "memory");
  asm volatile("s_barrier" ::: "memory");

  const u16* stA = srcA + 64;
  const u16* stB = srcB + 64;

  auto rd = [&](int s) {
#pragma unroll
    for (int f = 0; f < 4; ++f) bR[f].u = *(const uint4*)&lds[offB + s * 8192 + f * 512];
#pragma unroll
    for (int f = 0; f < 4; ++f) aR[f].u = *(const uint4*)&lds[offA + s * 4096 + f * 512];
  };
  auto mfma16 = [&]() {
    asm volatile("s_barrier" ::: "memory");
    asm volatile("s_waitcnt lgkmcnt(0)" ::: "memory");
    __builtin_amdgcn_s_setprio(1);
#pragma unroll
    for (int nf = 0; nf < 4; ++nf)
#pragma unroll
      for (int mf = 0; mf < 4; ++mf)
        acc[mf][nf] = __builtin_amdgcn_mfma_f32_16x16x32_bf16(aR[mf].v, bR[nf].v, acc[mf][nf], 0, 0, 0);
    __builtin_amdgcn_s_setprio(0);
  };

  for (int ktp = 0; ktp < NT; ktp += 2) {
    bool sAll = (ktp < NT - 2);
    // phase slot0 (kt=ktp, kk0); stage -> slot3 (t+1,kk1)
    rd(0);
    { gll16(stB + 32, ldsw + 24576); gll16(stB + 32 + rsB, ldsw + 28672); gll16(stA + 32, ldsw + 45056); }
    mfma16();
    asm volatile("s_waitcnt vmcnt(6)" ::: "memory");
    asm volatile("s_barrier" ::: "memory");
    // phase slot1 (kk1); stage -> slot0 (t+2,kk0)
    rd(1);
    if (sAll) { gll16(stB + 64, ldsw + 0); gll16(stB + 64 + rsB, ldsw + 4096); gll16(stA + 64, ldsw + 32768); }
    mfma16();
    if (sAll) asm volatile("s_waitcnt vmcnt(6)" ::: "memory");
    else asm volatile("s_waitcnt vmcnt(3)" ::: "memory");
    asm volatile("s_barrier" ::: "memory");
    // phase slot2 (kt=ktp+1, kk0); stage -> slot1 (t+2,kk1)
    rd(2);
    if (sAll) { gll16(stB + 96, ldsw + 8192); gll16(stB + 96 + rsB, ldsw + 12288); gll16(stA + 96, ldsw + 36864); }
    mfma16();
    if (sAll) asm volatile("s_waitcnt vmcnt(6)" ::: "memory");
    else asm volatile("s_waitcnt vmcnt(0)" ::: "memory");
    asm volatile("s_barrier" ::: "memory");
    // phase slot3 (kk1); stage -> slot2 (t+3,kk0)
    rd(3);
    if (sAll) { gll16(stB + 128, ldsw + 16384); gll16(stB + 128 + rsB, ldsw + 20480); gll16(stA + 128, ldsw + 40960); }
    mfma16();
    if (sAll) asm volatile("s_waitcnt vmcnt(6)" ::: "memory");
    asm volatile("s_barrier" ::: "memory");
    stA += 128; stB += 128;
  }

#pragma unroll
  for (int mf = 0; mf < 4; ++mf) {
#pragma unroll
    for (int rr = 0; rr < 4; ++rr) {
      int row = m0 + wm * 64 + mf * 16 + (lane >> 4) * 4 + rr;
#pragma unroll
      for (int nf = 0; nf < 4; ++nf) {
        int col = n0 + wn * 64 + nf * 16 + (lane & 15);
        float v = acc[mf][nf][rr];
        if (EPI == 0) {
          Cb[(size_t)row * N + col] = f2b(v);
        } else if (EPI == 1) {
          int b = row >> 10;
          Cf[(size_t)row * Hh + col] = hid[((size_t)b * Ss + idx[row]) * Hh + col] + v;
        } else {
          int b = row >> 10;
          Cf[((size_t)b * Ss + idx[row]) * Hh + col] = hs2[(size_t)row * Hh + col] + v * scalev[b];
        }
      }
    }
  }
}

// ---------------- RoPE on fused QKV buffer (stride 6144) ----------------
__global__ __launch_bounds__(256) void rope_qk(u16* __restrict__ qkv,
                                               const int* __restrict__ posg) {
  int gid = blockIdx.x * 256 + threadIdx.x;
  int i = gid & 63;
  int h = (gid >> 6) & 15;
  int t = gid >> 10;
  float p = (float)posg[t];
  float inv = exp2f(-(float)i * (13.287712379549449f / 64.0f));
  float ang = p * inv;
  float sv, cv;
  sincosf(ang, &sv, &cv);
  size_t base = (size_t)t * 6144 + h * DHh + i;
  u16* Q = qkv;
  u16* Kq = qkv + 2048;
  float q1 = b2f(Q[base]), q2 = b2f(Q[base + 64]);
  Q[base] = f2b(q1 * cv - q2 * sv);
  Q[base + 64] = f2b(q2 * cv + q1 * sv);
  float k1 = b2f(Kq[base]), k2 = b2f(Kq[base + 64]);
  Kq[base] = f2b(k1 * cv - k2 * sv);
  Kq[base + 64] = f2b(k2 * cv + k1 * sv);
}

// ---------------- flash attention over fused QKV (stride 6144) ----------------
__global__ __launch_bounds__(256) void attn_k(const u16* __restrict__ QKV, u16* __restrict__ O) {
  int qb = blockIdx.x;
  int head = blockIdx.y;
  int b = head >> 4, h = head & 15;
  int tid = threadIdx.x, lane = tid & 63, wv = tid >> 6;
  __shared__ __align__(16) u16 Ksm[32][136];
  __shared__ __align__(16) u16 Vs[128][40];
  __shared__ __align__(16) u16 Ps[4][16][40];
  int q0 = qb * 64 + wv * 16;
  int tokQ = b * KS + q0;
  B8 qf[4];
  const u16* qp = QKV + (size_t)(tokQ + (lane & 15)) * 6144 + h * DHh;
#pragma unroll
  for (int c = 0; c < 4; ++c) qf[c].u = *(const uint4*)(qp + c * 32 + (lane >> 4) * 8);
  float m_run = -1e30f, l_run = 0.0f;
  f32x4 oacc[8] = {};
  int kmax = qb * 64 + 64;
  for (int ks = 0; ks < kmax; ks += 32) {
    __syncthreads();
    for (int s = tid; s < 512; s += 256) {
      int key = s >> 4, d0 = (s & 15) * 8;
      size_t gb = (size_t)(b * KS + ks + key) * 6144 + 2048 + h * DHh + d0;
      uint4 kv = *(const uint4*)(QKV + gb);
      *(uint4*)&Ksm[key][d0] = kv;
      uint4 vv = *(const uint4*)(QKV + gb + 2048);
      u16* vp = (u16*)&vv;
      int kb = key >> 3, ko = key & 7;
#pragma unroll
      for (int j = 0; j < 8; ++j) {
        int d = d0 + j;
        Vs[d][((kb ^ ((d >> 3) & 3)) << 3) | ko] = vp[j];
      }
    }
    __syncthreads();
    f32x4 st[2] = {};
#pragma unroll
    for (int c = 0; c < 4; ++c) {
      B8 k0f, k1f;
      k0f.u = *(const uint4*)&Ksm[lane & 15][c * 32 + (lane >> 4) * 8];
      k1f.u = *(const uint4*)&Ksm[16 + (lane & 15)][c * 32 + (lane >> 4) * 8];
      st[0] = __builtin_amdgcn_mfma_f32_16x16x32_bf16(k0f.v, qf[c].v, st[0], 0, 0, 0);
      st[1] = __builtin_amdgcn_mfma_f32_16x16x32_bf16(k1f.v, qf[c].v, st[1], 0, 0, 0);
    }
    int qi = q0 + (lane & 15);
    float pmax = -INFINITY;
#pragma unroll
    for (int kt = 0; kt < 2; ++kt)
#pragma unroll
      for (int r = 0; r < 4; ++r) {
        int ki = ks + kt * 16 + (lane >> 4) * 4 + r;
        float v = st[kt][r] * 0.088388347648318447f;
        v = (ki <= qi) ? v : -INFINITY;
        st[kt][r] = v;
        pmax = fmaxf(pmax, v);
      }
    pmax = fmaxf(pmax, __shfl_xor(pmax, 16));
    pmax = fmaxf(pmax, __shfl_xor(pmax, 32));
    float m_new = fmaxf(m_run, pmax);
    float alpha = __expf(m_run - m_new);
    float psum = 0.0f;
#pragma unroll
    for (int kt = 0; kt < 2; ++kt)
#pragma unroll
      for (int r = 0; r < 4; ++r) {
        float pv = __expf(st[kt][r] - m_new);
        st[kt][r] = pv;
        psum += pv;
      }
    psum += __shfl_xor(psum, 16);
    psum += __shfl_xor(psum, 32);
    l_run = l_run * alpha + psum;
    m_run = m_new;
#pragma unroll
    for (int kt = 0; kt < 2; ++kt) {
      ushort4 pk;
      pk.x = f2b(st[kt][0]); pk.y = f2b(st[kt][1]);
      pk.z = f2b(st[kt][2]); pk.w = f2b(st[kt][3]);
      *(ushort4*)&Ps[wv][lane & 15][kt * 16 + (lane >> 4) * 4] = pk;
    }
    B8 pf;
    pf.u = *(const uint4*)&Ps[wv][lane & 15][(lane >> 4) * 8];
    float al0 = __shfl(alpha, (lane >> 4) * 4 + 0);
    float al1 = __shfl(alpha, (lane >> 4) * 4 + 1);
    float al2 = __shfl(alpha, (lane >> 4) * 4 + 2);
    float al3 = __shfl(alpha, (lane >> 4) * 4 + 3);
#pragma unroll
    for (int dt = 0; dt < 8; ++dt) {
      oacc[dt][0] *= al0; oacc[dt][1] *= al1;
      oacc[dt][2] *= al2; oacc[dt][3] *= al3;
    }
#pragma unroll
    for (int dt = 0; dt < 8; ++dt) {
      int d = dt * 16 + (lane & 15);
      B8 vf;
      vf.u = *(const uint4*)&Vs[d][(((lane >> 4) ^ ((d >> 3) & 3)) << 3)];
      oacc[dt] = __builtin_amdgcn_mfma_f32_16x16x32_bf16(pf.v, vf.v, oacc[dt], 0, 0, 0);
    }
  }
  float linv = 1.0f / l_run;
  float li[4];
#pragma unroll
  for (int r = 0; r < 4; ++r) li[r] = __shfl(linv, (lane >> 4) * 4 + r);
#pragma unroll
  for (int r = 0; r < 4; ++r) {
    int tok = tokQ + (lane >> 4) * 4 + r;
    u16* op = O + (size_t)tok * Hh + h * DHh;
#pragma unroll
    for (int dt = 0; dt < 8; ++dt) op[dt * 16 + (lane & 15)] = f2b(oacc[dt][r] * li[r]);
  }
}

// ---------------- silu(g)*u on fused gate|up buffer (stride 16384) ----------------
__global__ __launch_bounds__(256) void silu_gu(u16* __restrict__ gu) {
  size_t gid = (size_t)blockIdx.x * 256 + threadIdx.x;
  size_t t = gid >> 10;
  int c = (int)(gid & 1023) * 8;
  u16* gp = gu + t * 16384 + c;
  const u16* upp = gp + 8192;
  B8 gv, uv;
  gv.u = *(const uint4*)gp;
  uv.u = *(const uint4*)upp;
#pragma unroll
  for (int j = 0; j < 8; ++j) {
    float x = b2f(gv.s[j]), y = b2f(uv.s[j]);
    gv.s[j] = f2b(x / (1.0f + __expf(-x)) * y);
  }
  *(uint4*)gp = gv.u;
}

extern "C" void kernel_launch(void* const* d_in, const int* in_sizes, int n_in,
                              void* d_out, int out_size, void* d_ws, size_t ws_size,
                              hipStream_t stream) {
  (void)in_sizes; (void)n_in; (void)out_size; (void)ws_size;
  const float* hid = (const float*)d_in[0];
  const int* posids = (const int*)d_in[1];
  const void* mask = d_in[2];
  const float* scores = (const float*)d_in[3];
  const float* Wq = (const float*)d_in[5];
  const float* Wk = (const float*)d_in[6];
  const float* Wv = (const float*)d_in[7];
  const float* Wo = (const float*)d_in[8];
  const float* Wg = (const float*)d_in[9];
  const float* Wu = (const float*)d_in[10];
  const float* Wd = (const float*)d_in[11];
  const float* ln1 = (const float*)d_in[12];
  const float* ln2 = (const float*)d_in[13];
  float* out = (float*)d_out;
  char* ws = (char*)d_ws;

  u16* WqkvT = (u16*)(ws + 0);            // [6144][2048] bf16
  u16* WoT   = (u16*)(ws + 25165824);     // [2048][2048]
  u16* WguT  = (u16*)(ws + 33554432);     // [16384][2048]
  u16* WdT   = (u16*)(ws + 100663296);    // [2048][8192]
  int* idx   = (int*)(ws + 134217728);
  int* posg  = (int*)(ws + 134217728 + 16384);
  float* scalev = (float*)(ws + 134217728 + 32768);
  char* R = ws + 134283264;               // 128MiB pool
  u16* hsn    = (u16*)(R);                // [4096][2048]
  u16* qkv    = (u16*)(R + 16777216);     // [4096][6144]
  u16* attn_o = (u16*)(R + 67108864);     // [4096][2048]
  u16* gu     = (u16*)(R);                // [4096][16384] overlays (dead by then)
  float* hs2  = (float*)(ws + 268500992); // [4096][2048] f32
  u16* mnorm  = (u16*)(ws + 302055424);   // [4096][2048]

  hipMemcpyAsync(out, hid, (size_t)Bb * Ss * Hh * 4, hipMemcpyDeviceToDevice, stream);

  topk_prep<<<Bb, 256, 0, stream>>>(mask, posids, scores, idx, posg, scalev);

  transpose_w<<<dim3(64, 64), dim3(32, 8), 0, stream>>>(Wq, WqkvT, 2048, 2048);
  transpose_w<<<dim3(64, 64), dim3(32, 8), 0, stream>>>(Wk, WqkvT + 2048 * 2048, 2048, 2048);
  transpose_w<<<dim3(64, 64), dim3(32, 8), 0, stream>>>(Wv, WqkvT + 4096 * 2048, 2048, 2048);
  transpose_w<<<dim3(64, 64), dim3(32, 8), 0, stream>>>(Wo, WoT, 2048, 2048);
  transpose_w<<<dim3(256, 64), dim3(32, 8), 0, stream>>>(Wg, WguT, 2048, 8192);
  transpose_w<<<dim3(256, 64), dim3(32, 8), 0, stream>>>(Wu, WguT + 8192 * 2048, 2048, 8192);
  transpose_w<<<dim3(64, 256), dim3(32, 8), 0, stream>>>(Wd, WdT, 8192, 2048);

  rmsnorm_k<1><<<NTOK, 256, 0, stream>>>(hid, idx, ln1, hsn);

  // QKV fused: gemm128 (gm=32, gw=3) 768 blocks
  gemm128<0><<<768, 512, 0, stream>>>(hsn, WqkvT, 6144, 2048, 2048, 32, 3, qkv,
                                      nullptr, nullptr, nullptr, nullptr, nullptr);

  rope_qk<<<16384, 256, 0, stream>>>(qkv, posg);

  attn_k<<<dim3(16, 64), 256, 0, stream>>>(qkv, attn_o);

  // Wo: gemm128 (gm=32, gw=1) 256 blocks
  gemm128<1><<<256, 512, 0, stream>>>(attn_o, WoT, 2048, 2048, 2048, 32, 1, nullptr,
                                      hid, idx, nullptr, nullptr, hs2);

  rmsnorm_k<0><<<NTOK, 256, 0, stream>>>(hs2, nullptr, ln2, mnorm);

  // gate|up fused: gemm256 (gm=16, gw=8) 1024 blocks
  gemm256<0><<<1024, 512, 0, stream>>>(mnorm, WguT, 16384, 2048, 2048, 16, 8, gu,
                                       nullptr, nullptr, nullptr, nullptr, nullptr);

  silu_gu<<<16384, 256, 0, stream>>>(gu);

  // down: gemm128 (gm=32, gw=1) 256 blocks
  gemm128<2><<<256, 512, 0, stream>>>(gu, WdT, 2048, 8192, 16384, 32, 1, nullptr,
                                      nullptr, idx, hs2, scalev, out);
}